// Round 1
// 351.553 us; speedup vs baseline: 1.0767x; 1.0767x over previous
//
#include <hip/hip_runtime.h>
#include <hip/hip_bf16.h>
#include <stdint.h>

// Problem constants (fixed by reference: B=8, Q=4096, E=1024, M=256)
#define TOK 32768
#define EMB 1024
#define MSL 256

typedef __attribute__((ext_vector_type(8))) short short8;   // 8 bf16 = 4 VGPRs (MFMA A/B frag)
typedef __attribute__((ext_vector_type(4))) float f32x4;    // MFMA C/D frag

__device__ __forceinline__ ushort f2bf(float f) {
    union { float f; uint32_t u; } c; c.f = f;
    uint32_t u = c.u;
    return (ushort)((u + 0x7fffu + ((u >> 16) & 1u)) >> 16);  // RNE
}

// truncation split: f = hi + lo with |f - hi - lo| <= 2^-16 |f|
__device__ __forceinline__ void split2(float f, ushort& h, ushort& l) {
    union { float f; uint32_t u; } c; c.f = f;
    h = (ushort)(c.u >> 16);
    union { uint32_t u; float f; } hv; hv.u = c.u & 0xffff0000u;
    union { float f; uint32_t u; } lc; lc.f = f - hv.f;
    l = (ushort)(lc.u >> 16);
}

__device__ __forceinline__ void async_copy16(const void* gsrc, void* ldst) {
    // wave-uniform LDS base + lane*16 semantics (guide §5)
    __builtin_amdgcn_global_load_lds(
        (const __attribute__((address_space(1))) uint32_t*)gsrc,
        (__attribute__((address_space(3))) uint32_t*)ldst,
        16, 0, 0);
}

// ---------------- zero fp32 buffer (vectorized) ----------------
__global__ __launch_bounds__(256) void zero_f32(float* __restrict__ p) {
    int i = blockIdx.x * 256 + threadIdx.x;
    ((float4*)p)[i] = float4{0.f, 0.f, 0.f, 0.f};
}

// ---------------- fp32 -> bf16 cast ----------------
__global__ __launch_bounds__(256) void cast_f32_bf16(const float* __restrict__ in,
                                                     ushort* __restrict__ out) {
    int i = blockIdx.x * 256 + threadIdx.x;
    float4 v = ((const float4*)in)[i];
    ushort4 o;
    o.x = f2bf(v.x); o.y = f2bf(v.y); o.z = f2bf(v.z); o.w = f2bf(v.w);
    ((ushort4*)out)[i] = o;
}

// ---------------- fp32 -> (hi, lo) bf16 split, vectorized ----------------
__global__ __launch_bounds__(256) void split_f32(const float* __restrict__ in,
                                                 ushort* __restrict__ hi,
                                                 ushort* __restrict__ lo) {
    int i = blockIdx.x * 256 + threadIdx.x;          // grid = n/4/256
    float4 v = ((const float4*)in)[i];
    ushort4 h4, l4;
    split2(v.x, h4.x, l4.x); split2(v.y, h4.y, l4.y);
    split2(v.z, h4.z, l4.z); split2(v.w, h4.w, l4.w);
    ((ushort4*)hi)[i] = h4;
    ((ushort4*)lo)[i] = l4;
}

// ---------------- Wq [F][E] -> WqT hi/lo [E][F], LDS-tiled 64x64 ----------------
__global__ __launch_bounds__(256) void transpose_split(const float* __restrict__ in,
                                                       ushort* __restrict__ outh,
                                                       ushort* __restrict__ outl) {
    __shared__ float ld[64 * 65];
    const int t = threadIdx.x;
    const int eBase = blockIdx.x * 64;
    const int fBase = blockIdx.y * 64;
    #pragma unroll
    for (int r = 0; r < 16; ++r) {
        int row = r * 4 + (t >> 6);      // f within tile
        int col = t & 63;                // e within tile
        ld[row * 65 + col] = in[(size_t)(fBase + row) * EMB + eBase + col];
    }
    __syncthreads();
    #pragma unroll
    for (int r = 0; r < 16; ++r) {
        int row = r * 4 + (t >> 6);      // e within tile
        int col = t & 63;                // f within tile
        float v = ld[col * 65 + row];    // = in[fBase+col][eBase+row]
        ushort h, l; split2(v, h, l);
        size_t o = (size_t)(eBase + row) * EMB + fBase + col;
        outh[o] = h; outl[o] = l;
    }
}

// ---------------- c[m] = dot(bq, mb[m]) , one wave per m ----------------
__global__ __launch_bounds__(256) void dot_c(const float* __restrict__ bq,
                                             const float* __restrict__ mb,
                                             float* __restrict__ c) {
    int m = blockIdx.x * 4 + (threadIdx.x >> 6);
    int lane = threadIdx.x & 63;
    const float4* mrow = (const float4*)(mb + (size_t)m * EMB);
    const float4* brow = (const float4*)bq;
    float s = 0.f;
    #pragma unroll
    for (int k = 0; k < 4; ++k) {
        float4 a = mrow[lane + k * 64];
        float4 b = brow[lane + k * 64];
        s += a.x * b.x + a.y * b.y + a.z * b.z + a.w * b.w;
    }
    #pragma unroll
    for (int off = 32; off; off >>= 1) s += __shfl_xor(s, off, 64);
    if (lane == 0) c[m] = s;
}

// XOR swizzle: LDS slot (row, c) holds global 16B-chunk (c ^ (row&7)) of that row.
// Writers keep lane-flat LDS addresses (global source permuted -> same coalescing);
// readers XOR the chunk column by row&7 -> 16-lane phases spread over all 32 banks.

// ---- split-precision GEMM: C[n,c] = sum_k A_f32[n,k] * (Bh+Bl)[c,k] (+bias[c]) ----
// C = Ah*Bh + Ah*Bl + Al*Bh  (fp32 MFMA accumulate) -> ~fp32 precision.
// Block tile 128x128, BK=64, 256 threads = 4 waves (2x2), wave tile 64x64.
// ATOMIC: split-K over gridDim.z, fp32 atomicAdd epilogue (buffer must be pre-zeroed).
template<bool ADD_BIAS, bool OUT_BF16, bool ATOMIC>
__global__ __launch_bounds__(256) void gemm_s(
    const float* __restrict__ A, const ushort* __restrict__ Bh,
    const ushort* __restrict__ Bl, const float* __restrict__ bias,
    void* __restrict__ Cout, int K, int ldc)
{
    __shared__ ushort sAh[128 * 64];   // 16 KiB each, 64 KiB total
    __shared__ ushort sAl[128 * 64];
    __shared__ ushort sBh[128 * 64];
    __shared__ ushort sBl[128 * 64];

    const int t = threadIdx.x;
    const int lane = t & 63;
    const int wave = t >> 6;
    const int wr = wave >> 1;
    const int wc = wave & 1;
    const int rowBase = blockIdx.y * 128;
    const int colBase = blockIdx.x * 128;

    const float*  Ab  = A  + (size_t)rowBase * K;
    const ushort* Bhb = Bh + (size_t)colBase * K;
    const ushort* Blb = Bl + (size_t)colBase * K;

    // staging source-chunk permutation (constant per thread)
    const int cg = ((t & 7) ^ ((t >> 3) & 7)) << 3;   // element offset of swizzled chunk

    f32x4 acc[4][4] = {};

    const int kIters = (K >> 6) / (ATOMIC ? gridDim.z : 1);
    const int ktBase = ATOMIC ? blockIdx.z * kIters : 0;
    for (int kt = ktBase; kt < ktBase + kIters; ++kt) {
        const int k0 = kt << 6;
        __syncthreads();
        // B tiles: async global->LDS (bf16, pre-split), swizzled source
        #pragma unroll
        for (int r = 0; r < 4; ++r) {
            int row = r * 32 + (t >> 3);
            async_copy16(Bhb + (size_t)row * K + k0 + cg, &sBh[(size_t)(r * 256 + wave * 64) * 8]);
            async_copy16(Blb + (size_t)row * K + k0 + cg, &sBl[(size_t)(r * 256 + wave * 64) * 8]);
        }
        // A tile: fp32 load (swizzled source) -> in-register split -> LDS hi/lo
        #pragma unroll
        for (int r = 0; r < 4; ++r) {
            int i = r * 256 + t;
            int row = r * 32 + (t >> 3);
            const float* src = Ab + (size_t)row * K + k0 + cg;
            float4 f0 = *(const float4*)src;
            float4 f1 = *(const float4*)(src + 4);
            short8 hv, lv; ushort h, l;
            split2(f0.x, h, l); hv[0] = (short)h; lv[0] = (short)l;
            split2(f0.y, h, l); hv[1] = (short)h; lv[1] = (short)l;
            split2(f0.z, h, l); hv[2] = (short)h; lv[2] = (short)l;
            split2(f0.w, h, l); hv[3] = (short)h; lv[3] = (short)l;
            split2(f1.x, h, l); hv[4] = (short)h; lv[4] = (short)l;
            split2(f1.y, h, l); hv[5] = (short)h; lv[5] = (short)l;
            split2(f1.z, h, l); hv[6] = (short)h; lv[6] = (short)l;
            split2(f1.w, h, l); hv[7] = (short)h; lv[7] = (short)l;
            *(short8*)&sAh[(size_t)i * 8] = hv;
            *(short8*)&sAl[(size_t)i * 8] = lv;
        }
        __syncthreads();

        #pragma unroll
        for (int ks = 0; ks < 2; ++ks) {
            const int kc = ks * 4 + (lane >> 4);      // 16B chunk column
            short8 ah[4], al[4], bh[4], bl[4];
            #pragma unroll
            for (int i2 = 0; i2 < 4; ++i2) {
                int row = wr * 64 + i2 * 16 + (lane & 15);
                int off = row * 64 + ((kc ^ (row & 7)) << 3);
                ah[i2] = *(const short8*)&sAh[off];
                al[i2] = *(const short8*)&sAl[off];
            }
            #pragma unroll
            for (int j = 0; j < 4; ++j) {
                int row = wc * 64 + j * 16 + (lane & 15);
                int off = row * 64 + ((kc ^ (row & 7)) << 3);
                bh[j] = *(const short8*)&sBh[off];
                bl[j] = *(const short8*)&sBl[off];
            }
            #pragma unroll
            for (int i2 = 0; i2 < 4; ++i2)
                #pragma unroll
                for (int j = 0; j < 4; ++j) {
                    acc[i2][j] = __builtin_amdgcn_mfma_f32_16x16x32_bf16(ah[i2], bh[j], acc[i2][j], 0, 0, 0);
                    acc[i2][j] = __builtin_amdgcn_mfma_f32_16x16x32_bf16(ah[i2], bl[j], acc[i2][j], 0, 0, 0);
                    acc[i2][j] = __builtin_amdgcn_mfma_f32_16x16x32_bf16(al[i2], bh[j], acc[i2][j], 0, 0, 0);
                }
        }
    }

    // epilogue: C/D layout col=lane&15, row=(lane>>4)*4+reg  [verified m89/m91]
    #pragma unroll
    for (int i2 = 0; i2 < 4; ++i2) {
        #pragma unroll
        for (int j = 0; j < 4; ++j) {
            const int col = colBase + wc * 64 + j * 16 + (lane & 15);
            float bcol = ADD_BIAS ? bias[col] : 0.0f;
            #pragma unroll
            for (int r = 0; r < 4; ++r) {
                const int row = rowBase + wr * 64 + i2 * 16 + ((lane >> 4) << 2) + r;
                float v = acc[i2][j][r] + bcol;
                if (ATOMIC)
                    atomicAdd(&((float*)Cout)[(size_t)row * ldc + col], v);
                else if (OUT_BF16)
                    ((ushort*)Cout)[(size_t)row * ldc + col] = f2bf(v);
                else
                    ((float*)Cout)[(size_t)row * ldc + col] = v;
            }
        }
    }
}

// =====================================================================
// Fused: scores (split-precision) + softmax + PV + bias + residual.
// One block per 128 tokens (grid=256 = 1 block/CU), 512 threads = 8 waves.
// Phase 1: scores[128x256] = x @ (Ph+Pl)^T + c  (3-MFMA split, as gemm_s)
//   wave grid 2x4: wave tile 64 rows x 64 cols. acc[4][4].
// Softmax: per-row; 16-lane shfl groups + 4-way cross-wave combine via LDS.
// Weights -> swizzled LDS [128][256] bf16.
// Phase 2: out = w @ RT^T + bo + x. Weight A-frags held in registers across
//   16 column chunks of 64; RT chunks double-buffered via global_load_lds.
// LDS map (ushort elems):
//   phase1: sAh 0..8191, sAl 8192..16383, sBh 16384..32767, sBl 32768..49151
//   sW (phase2 A)  0..32767   (overlays sAh/sAl/sBh after phase1 barrier)
//   sRT buf0 32768..49151, buf1 49152..65535 (dbuf)
//   redM/redS (softmax) alias 49152..51199 (dead before buf1 first staged)
// =====================================================================
__global__ __launch_bounds__(512, 2) void fused_attn(
    const float* __restrict__ x, const ushort* __restrict__ Ph,
    const ushort* __restrict__ Pl, const float* __restrict__ cvec,
    const ushort* __restrict__ RTb, const float* __restrict__ bo,
    float* __restrict__ out)
{
    __shared__ ushort smem[65536];            // 128 KiB
    ushort* sAh = smem;                       // [128][64]
    ushort* sAl = smem + 8192;
    ushort* sBh = smem + 16384;               // [256][64]
    ushort* sBl = smem + 32768;
    ushort* sW  = smem;                       // [128][256] swizzled (phase 2)
    float*  redM = (float*)&smem[49152];      // [4][128] partial max
    float*  redS = (float*)&smem[50176];      // [4][128] partial sum

    const int t = threadIdx.x;
    const int lane = t & 63;
    const int wave = t >> 6;                  // 0..7
    const int wr = wave >> 2;                 // 0..1 : rows wr*64
    const int wc = wave & 3;                  // 0..3 : cols wc*64
    const int rowBase = blockIdx.x * 128;

    const float* Ab = x + (size_t)rowBase * EMB;
    const int cg = ((t & 7) ^ ((t >> 3) & 7)) << 3;

    f32x4 acc[4][4] = {};

    // ---------------- phase 1: scores ----------------
    for (int kt = 0; kt < 16; ++kt) {
        const int k0 = kt << 6;
        __syncthreads();
        // B tiles (Ph/Pl) 256x64: async, swizzled source
        #pragma unroll
        for (int r = 0; r < 4; ++r) {
            int row = r * 64 + (t >> 3);
            async_copy16(Ph + (size_t)row * EMB + k0 + cg, &sBh[(size_t)(r * 512 + wave * 64) * 8]);
            async_copy16(Pl + (size_t)row * EMB + k0 + cg, &sBl[(size_t)(r * 512 + wave * 64) * 8]);
        }
        // A tile 128x64 fp32 -> split -> LDS
        #pragma unroll
        for (int r = 0; r < 2; ++r) {
            int i = r * 512 + t;
            int row = r * 64 + (t >> 3);
            const float* src = Ab + (size_t)row * EMB + k0 + cg;
            float4 f0 = *(const float4*)src;
            float4 f1 = *(const float4*)(src + 4);
            short8 hv, lv; ushort h, l;
            split2(f0.x, h, l); hv[0] = (short)h; lv[0] = (short)l;
            split2(f0.y, h, l); hv[1] = (short)h; lv[1] = (short)l;
            split2(f0.z, h, l); hv[2] = (short)h; lv[2] = (short)l;
            split2(f0.w, h, l); hv[3] = (short)h; lv[3] = (short)l;
            split2(f1.x, h, l); hv[4] = (short)h; lv[4] = (short)l;
            split2(f1.y, h, l); hv[5] = (short)h; lv[5] = (short)l;
            split2(f1.z, h, l); hv[6] = (short)h; lv[6] = (short)l;
            split2(f1.w, h, l); hv[7] = (short)h; lv[7] = (short)l;
            *(short8*)&sAh[(size_t)i * 8] = hv;
            *(short8*)&sAl[(size_t)i * 8] = lv;
        }
        __syncthreads();

        #pragma unroll
        for (int ks = 0; ks < 2; ++ks) {
            const int kc = ks * 4 + (lane >> 4);
            short8 ah[4], al[4], bh[4], bl[4];
            #pragma unroll
            for (int i2 = 0; i2 < 4; ++i2) {
                int row = wr * 64 + i2 * 16 + (lane & 15);
                int off = row * 64 + ((kc ^ (row & 7)) << 3);
                ah[i2] = *(const short8*)&sAh[off];
                al[i2] = *(const short8*)&sAl[off];
            }
            #pragma unroll
            for (int j = 0; j < 4; ++j) {
                int row = wc * 64 + j * 16 + (lane & 15);
                int off = row * 64 + ((kc ^ (row & 7)) << 3);
                bh[j] = *(const short8*)&sBh[off];
                bl[j] = *(const short8*)&sBl[off];
            }
            #pragma unroll
            for (int i2 = 0; i2 < 4; ++i2)
                #pragma unroll
                for (int j = 0; j < 4; ++j) {
                    acc[i2][j] = __builtin_amdgcn_mfma_f32_16x16x32_bf16(ah[i2], bh[j], acc[i2][j], 0, 0, 0);
                    acc[i2][j] = __builtin_amdgcn_mfma_f32_16x16x32_bf16(ah[i2], bl[j], acc[i2][j], 0, 0, 0);
                    acc[i2][j] = __builtin_amdgcn_mfma_f32_16x16x32_bf16(al[i2], bh[j], acc[i2][j], 0, 0, 0);
                }
        }
    }

    // ---------------- softmax (rows local to block; cols split over 4 wc) ----------------
    // add c[m]
    {
        float cj[4];
        #pragma unroll
        for (int j = 0; j < 4; ++j) cj[j] = cvec[wc * 64 + j * 16 + (lane & 15)];
        #pragma unroll
        for (int i2 = 0; i2 < 4; ++i2)
            #pragma unroll
            for (int j = 0; j < 4; ++j)
                #pragma unroll
                for (int r = 0; r < 4; ++r) acc[i2][j][r] += cj[j];
    }
    // partial row max over this wave's 64 cols
    {
        float pmax[4][4];
        #pragma unroll
        for (int i2 = 0; i2 < 4; ++i2)
            #pragma unroll
            for (int r = 0; r < 4; ++r) {
                float m0 = fmaxf(fmaxf(acc[i2][0][r], acc[i2][1][r]),
                                 fmaxf(acc[i2][2][r], acc[i2][3][r]));
                #pragma unroll
                for (int off = 8; off; off >>= 1) m0 = fmaxf(m0, __shfl_xor(m0, off, 64));
                pmax[i2][r] = m0;
            }
        if ((lane & 15) == 0) {
            #pragma unroll
            for (int i2 = 0; i2 < 4; ++i2)
                #pragma unroll
                for (int r = 0; r < 4; ++r)
                    redM[wc * 128 + wr * 64 + i2 * 16 + ((lane >> 4) << 2) + r] = pmax[i2][r];
        }
    }
    __syncthreads();   // also: all phase-1 LDS reads complete
    // full max, exp, partial sum
    {
        float psum[4][4];
        #pragma unroll
        for (int i2 = 0; i2 < 4; ++i2)
            #pragma unroll
            for (int r = 0; r < 4; ++r) {
                int R = wr * 64 + i2 * 16 + ((lane >> 4) << 2) + r;
                float mx = fmaxf(fmaxf(redM[R], redM[128 + R]),
                                 fmaxf(redM[256 + R], redM[384 + R]));
                float s = 0.f;
                #pragma unroll
                for (int j = 0; j < 4; ++j) {
                    float e = __expf(acc[i2][j][r] - mx);
                    acc[i2][j][r] = e;
                    s += e;
                }
                #pragma unroll
                for (int off = 8; off; off >>= 1) s += __shfl_xor(s, off, 64);
                psum[i2][r] = s;
            }
        if ((lane & 15) == 0) {
            #pragma unroll
            for (int i2 = 0; i2 < 4; ++i2)
                #pragma unroll
                for (int r = 0; r < 4; ++r)
                    redS[wc * 128 + wr * 64 + i2 * 16 + ((lane >> 4) << 2) + r] = psum[i2][r];
        }
    }
    __syncthreads();
    // normalize -> bf16 weights -> swizzled sW[128][256]
    #pragma unroll
    for (int i2 = 0; i2 < 4; ++i2)
        #pragma unroll
        for (int r = 0; r < 4; ++r) {
            int R = wr * 64 + i2 * 16 + ((lane >> 4) << 2) + r;
            float tot = redS[R] + redS[128 + R] + redS[256 + R] + redS[384 + R];
            float inv = 1.0f / tot;
            #pragma unroll
            for (int j = 0; j < 4; ++j) {
                int col = wc * 64 + j * 16 + (lane & 15);
                int cc = col >> 3;
                int slot = (cc & 24) | ((cc & 7) ^ (R & 7));
                sW[R * 256 + slot * 8 + (lane & 7)] = f2bf(acc[i2][j][r] * inv);
            }
        }

    // ---------------- phase 2: out = w @ RT^T + bo + x ----------------
    // stage RT chunk fcn (64 f-rows x 256 m) into sRT buffer `buf`
    auto stage_rt = [&](int fcn, int buf) {
        const ushort* src = RTb + (size_t)(fcn * 64) * MSL;
        ushort* dstb = smem + 32768 + buf * 16384;
        #pragma unroll
        for (int r = 0; r < 4; ++r) {
            int fr = r * 16 + (t >> 5);
            int c = t & 31;
            int gc = (c & 24) | ((c & 7) ^ (fr & 7));
            async_copy16(src + (size_t)fr * MSL + gc * 8,
                         &dstb[(size_t)(r * 512 + wave * 64) * 8]);
        }
    };
    stage_rt(0, 0);
    __syncthreads();   // sW visible to all waves, chunk 0 staged (vmcnt drained)

    const int wr2 = wave >> 1;    // 0..3 : rows wr2*32
    const int wc2 = wave & 1;     // 0..1 : cols wc2*32 within a 64-col chunk

    // preload weight A-frags from sW: held in regs across all 16 chunks
    short8 af[2][8];
    #pragma unroll
    for (int i2 = 0; i2 < 2; ++i2) {
        int R = wr2 * 32 + i2 * 16 + (lane & 15);
        #pragma unroll
        for (int ks2 = 0; ks2 < 8; ++ks2) {
            int cc = ks2 * 4 + (lane >> 4);
            int slot = (cc & 24) | ((cc & 7) ^ (R & 7));
            af[i2][ks2] = *(const short8*)&sW[R * 256 + slot * 8];
        }
    }

    for (int fc = 0; fc < 16; ++fc) {
        if (fc < 15) stage_rt(fc + 1, (fc + 1) & 1);
        const ushort* bufp = smem + 32768 + (fc & 1) * 16384;
        f32x4 acc2[2][2] = {};
        #pragma unroll
        for (int ks2 = 0; ks2 < 8; ++ks2) {
            int cc = ks2 * 4 + (lane >> 4);
            short8 b[2];
            #pragma unroll
            for (int j = 0; j < 2; ++j) {
                int frow = wc2 * 32 + j * 16 + (lane & 15);
                int slot = (cc & 24) | ((cc & 7) ^ (frow & 7));
                b[j] = *(const short8*)&bufp[frow * 256 + slot * 8];
            }
            #pragma unroll
            for (int i2 = 0; i2 < 2; ++i2)
                #pragma unroll
                for (int j = 0; j < 2; ++j)
                    acc2[i2][j] = __builtin_amdgcn_mfma_f32_16x16x32_bf16(
                        af[i2][ks2], b[j], acc2[i2][j], 0, 0, 0);
        }
        // epilogue: + bias + residual, fp32 store
        #pragma unroll
        for (int i2 = 0; i2 < 2; ++i2)
            #pragma unroll
            for (int j = 0; j < 2; ++j) {
                int col = fc * 64 + wc2 * 32 + j * 16 + (lane & 15);
                float bcol = bo[col];
                #pragma unroll
                for (int r = 0; r < 4; ++r) {
                    int row = rowBase + wr2 * 32 + i2 * 16 + ((lane >> 4) << 2) + r;
                    out[(size_t)row * EMB + col] =
                        acc2[i2][j][r] + bcol + x[(size_t)row * EMB + col];
                }
            }
        __syncthreads();   // next chunk staged; all reads of current buf done
    }
}

extern "C" void kernel_launch(void* const* d_in, const int* in_sizes, int n_in,
                              void* d_out, int out_size, void* d_ws, size_t ws_size,
                              hipStream_t stream) {
    const float* x  = (const float*)d_in[0];   // [TOK, EMB]
    const float* mb = (const float*)d_in[1];   // [MSL, EMB]
    const float* Wq = (const float*)d_in[2];   // [EMB, EMB]
    const float* bq = (const float*)d_in[3];   // [EMB]
    const float* Wo = (const float*)d_in[4];   // [EMB, EMB]
    const float* bo = (const float*)d_in[5];   // [EMB]
    float* out = (float*)d_out;                // [TOK, EMB]

    // workspace layout (~10 MB). P and RTf adjacent -> single zero pass.
    char* ws = (char*)d_ws;
    size_t o = 0;
    float*  P    = (float*)(ws + o);  o += (size_t)MSL * EMB * 4;   // P fp32 (atomic dst)
    float*  RTf  = (float*)(ws + o);  o += (size_t)EMB * MSL * 4;   // RT fp32 (atomic dst)
    ushort* mbh  = (ushort*)(ws + o); o += (size_t)MSL * EMB * 2;   // mb hi
    ushort* mbl  = (ushort*)(ws + o); o += (size_t)MSL * EMB * 2;   // mb lo
    ushort* wqth = (ushort*)(ws + o); o += (size_t)EMB * EMB * 2;   // Wq^T hi
    ushort* wqtl = (ushort*)(ws + o); o += (size_t)EMB * EMB * 2;   // Wq^T lo
    ushort* Ph   = (ushort*)(ws + o); o += (size_t)MSL * EMB * 2;
    ushort* Pl   = (ushort*)(ws + o); o += (size_t)MSL * EMB * 2;
    ushort* RTb  = (ushort*)(ws + o); o += (size_t)EMB * MSL * 2;   // RT bf16 [EMB, MSL]
    float*  cvec = (float*)(ws + o);  o += (size_t)MSL * 4;

    // zero atomic destinations (P + RTf contiguous: 2*MSL*EMB floats)
    zero_f32<<<(2 * MSL * EMB / 4) / 256, 256, 0, stream>>>(P);

    // --- small precomputes (fold the fixed memory bank into the projections) ---
    split_f32<<<(MSL * EMB / 4) / 256, 256, 0, stream>>>(mb, mbh, mbl);
    transpose_split<<<dim3(16, 16), 256, 0, stream>>>(Wq, wqth, wqtl);
    dot_c<<<MSL / 4, 256, 0, stream>>>(bq, mb, cvec);

    // P[m,e] = sum_f mb[m,f] * WqT[e,f]  — split-K (16 chunks), atomic fp32
    gemm_s<false, false, true><<<dim3(EMB / 128, MSL / 128, 16), 256, 0, stream>>>(
        mb, wqth, wqtl, nullptr, P, EMB, EMB);
    split_f32<<<(MSL * EMB / 4) / 256, 256, 0, stream>>>(P, Ph, Pl);

    // RT[f,m] = sum_e Wo[f,e] * mb[m,e]  — split-K, atomic fp32, then cast
    gemm_s<false, false, true><<<dim3(MSL / 128, EMB / 128, 16), 256, 0, stream>>>(
        Wo, mbh, mbl, nullptr, RTf, EMB, MSL);
    cast_f32_bf16<<<(EMB * MSL / 4) / 256, 256, 0, stream>>>(RTf, RTb);

    // fused: scores + softmax + PV + bias + residual (one block per 128 tokens)
    fused_attn<<<TOK / 128, 512, 0, stream>>>(x, Ph, Pl, cvec, RTb, bo, out);
}

// Round 2
// 350.671 us; speedup vs baseline: 1.0794x; 1.0025x over previous
//
#include <hip/hip_runtime.h>
#include <hip/hip_bf16.h>
#include <stdint.h>

// Problem constants (fixed by reference: B=8, Q=4096, E=1024, M=256)
#define TOK 32768
#define EMB 1024
#define MSL 256

typedef __attribute__((ext_vector_type(8))) short short8;   // 8 bf16 = 4 VGPRs (MFMA A/B frag)
typedef __attribute__((ext_vector_type(4))) float f32x4;    // MFMA C/D frag

__device__ __forceinline__ ushort f2bf(float f) {
    union { float f; uint32_t u; } c; c.f = f;
    uint32_t u = c.u;
    return (ushort)((u + 0x7fffu + ((u >> 16) & 1u)) >> 16);  // RNE
}

// truncation split: f = hi + lo with |f - hi - lo| <= 2^-16 |f|
__device__ __forceinline__ void split2(float f, ushort& h, ushort& l) {
    union { float f; uint32_t u; } c; c.f = f;
    h = (ushort)(c.u >> 16);
    union { uint32_t u; float f; } hv; hv.u = c.u & 0xffff0000u;
    union { float f; uint32_t u; } lc; lc.f = f - hv.f;
    l = (ushort)(lc.u >> 16);
}

__device__ __forceinline__ void async_copy16(const void* gsrc, void* ldst) {
    // wave-uniform LDS base + lane*16 semantics (guide §5)
    __builtin_amdgcn_global_load_lds(
        (const __attribute__((address_space(1))) uint32_t*)gsrc,
        (__attribute__((address_space(3))) uint32_t*)ldst,
        16, 0, 0);
}

// XOR swizzle: LDS slot (row, c) holds global 16B-chunk (c ^ (row&7)) of that row.
// Writers keep lane-flat LDS addresses (global source permuted -> same coalescing);
// readers XOR the chunk column by row&7 -> 16-lane phases spread over all 32 banks.

// =====================================================================
// pre_small: merged tiny precomputes (all independent of each other)
//   blocks 0..255   : Wq [F][E] -> WqT hi/lo [E][F]  (64x64 LDS transpose)
//   blocks 256..511 : mb fp32 -> mbh/mbl bf16 split
//   blocks 512..575 : cvec[m] = dot(bq, mb[m])  (one wave per m)
// =====================================================================
__global__ __launch_bounds__(256) void pre_small(
    const float* __restrict__ Wq, ushort* __restrict__ wqth, ushort* __restrict__ wqtl,
    const float* __restrict__ mb, ushort* __restrict__ mbh, ushort* __restrict__ mbl,
    const float* __restrict__ bq, float* __restrict__ cvec)
{
    __shared__ float ld[64 * 65];
    const int b = blockIdx.x;
    const int t = threadIdx.x;
    if (b < 256) {
        const int eBase = (b & 15) * 64;
        const int fBase = (b >> 4) * 64;
        #pragma unroll
        for (int r = 0; r < 16; ++r) {
            int row = r * 4 + (t >> 6);      // f within tile
            int col = t & 63;                // e within tile
            ld[row * 65 + col] = Wq[(size_t)(fBase + row) * EMB + eBase + col];
        }
        __syncthreads();
        #pragma unroll
        for (int r = 0; r < 16; ++r) {
            int row = r * 4 + (t >> 6);      // e within tile
            int col = t & 63;                // f within tile
            float v = ld[col * 65 + row];    // = Wq[fBase+col][eBase+row]
            ushort h, l; split2(v, h, l);
            size_t o = (size_t)(eBase + row) * EMB + fBase + col;
            wqth[o] = h; wqtl[o] = l;
        }
    } else if (b < 512) {
        int i = (b - 256) * 256 + t;         // mb: 256*1024/4 float4s
        float4 v = ((const float4*)mb)[i];
        ushort4 h4, l4;
        split2(v.x, h4.x, l4.x); split2(v.y, h4.y, l4.y);
        split2(v.z, h4.z, l4.z); split2(v.w, h4.w, l4.w);
        ((ushort4*)mbh)[i] = h4;
        ((ushort4*)mbl)[i] = l4;
    } else {
        int m = (b - 512) * 4 + (t >> 6);
        int lane = t & 63;
        const float4* mrow = (const float4*)(mb + (size_t)m * EMB);
        const float4* brow = (const float4*)bq;
        float s = 0.f;
        #pragma unroll
        for (int k = 0; k < 4; ++k) {
            float4 a = mrow[lane + k * 64];
            float4 bb = brow[lane + k * 64];
            s += a.x * bb.x + a.y * bb.y + a.z * bb.z + a.w * bb.w;
        }
        #pragma unroll
        for (int off = 32; off; off >>= 1) s += __shfl_xor(s, off, 64);
        if (lane == 0) cvec[m] = s;
    }
}

// =====================================================================
// Split-precision GEMM body: C[row,col] = sum_k A_f32[row,k]*(Bh+Bl)[col,k]
// (Ah*Bh + Ah*Bl + Al*Bh, fp32 MFMA accumulate -> ~fp32 precision)
// Block tile 128x128, BK=64, 256 threads = 4 waves (2x2), wave tile 64x64.
// No split-K, no atomics. Epilogue:
//   MODE 0: split2(v) -> O1 (hi) / O2 (lo), row-major ldc
//   MODE 1: f2bf(v) -> O1 in phase-2 MFMA fragment layout:
//           f=row, m=col; fc=f>>6, jj=(f&63)>>4, lanelo=f&15;
//           cc=m>>3, ks=cc>>2, lanehi=cc&3, lane=lanehi*16+lanelo, e=m&7;
//           idx = (((fc*8+ks)*4+jj)*64+lane)*8 + e
// =====================================================================
template<int MODE>
__device__ __forceinline__ void gemm_body(
    ushort* smem, const float* __restrict__ A,
    const ushort* __restrict__ Bh, const ushort* __restrict__ Bl,
    ushort* __restrict__ O1, ushort* __restrict__ O2,
    int K, int ldc, int bx, int by)
{
    ushort* sAh = smem;            // [128][64] = 8192 ushorts each
    ushort* sAl = smem + 8192;
    ushort* sBh = smem + 16384;
    ushort* sBl = smem + 24576;

    const int t = threadIdx.x;
    const int lane = t & 63;
    const int wave = t >> 6;
    const int wr = wave >> 1;
    const int wc = wave & 1;
    const int rowBase = by * 128;
    const int colBase = bx * 128;

    const float*  Ab  = A  + (size_t)rowBase * K;
    const ushort* Bhb = Bh + (size_t)colBase * K;
    const ushort* Blb = Bl + (size_t)colBase * K;

    const int cg = ((t & 7) ^ ((t >> 3) & 7)) << 3;

    f32x4 acc[4][4] = {};

    const int kIters = K >> 6;
    for (int kt = 0; kt < kIters; ++kt) {
        const int k0 = kt << 6;
        __syncthreads();
        #pragma unroll
        for (int r = 0; r < 4; ++r) {
            int row = r * 32 + (t >> 3);
            async_copy16(Bhb + (size_t)row * K + k0 + cg, &sBh[(size_t)(r * 256 + wave * 64) * 8]);
            async_copy16(Blb + (size_t)row * K + k0 + cg, &sBl[(size_t)(r * 256 + wave * 64) * 8]);
        }
        #pragma unroll
        for (int r = 0; r < 4; ++r) {
            int i = r * 256 + t;
            int row = r * 32 + (t >> 3);
            const float* src = Ab + (size_t)row * K + k0 + cg;
            float4 f0 = *(const float4*)src;
            float4 f1 = *(const float4*)(src + 4);
            short8 hv, lv; ushort h, l;
            split2(f0.x, h, l); hv[0] = (short)h; lv[0] = (short)l;
            split2(f0.y, h, l); hv[1] = (short)h; lv[1] = (short)l;
            split2(f0.z, h, l); hv[2] = (short)h; lv[2] = (short)l;
            split2(f0.w, h, l); hv[3] = (short)h; lv[3] = (short)l;
            split2(f1.x, h, l); hv[4] = (short)h; lv[4] = (short)l;
            split2(f1.y, h, l); hv[5] = (short)h; lv[5] = (short)l;
            split2(f1.z, h, l); hv[6] = (short)h; lv[6] = (short)l;
            split2(f1.w, h, l); hv[7] = (short)h; lv[7] = (short)l;
            *(short8*)&sAh[(size_t)i * 8] = hv;
            *(short8*)&sAl[(size_t)i * 8] = lv;
        }
        __syncthreads();

        #pragma unroll
        for (int ks = 0; ks < 2; ++ks) {
            const int kc = ks * 4 + (lane >> 4);
            short8 ah[4], al[4], bh[4], bl[4];
            #pragma unroll
            for (int i2 = 0; i2 < 4; ++i2) {
                int row = wr * 64 + i2 * 16 + (lane & 15);
                int off = row * 64 + ((kc ^ (row & 7)) << 3);
                ah[i2] = *(const short8*)&sAh[off];
                al[i2] = *(const short8*)&sAl[off];
            }
            #pragma unroll
            for (int j = 0; j < 4; ++j) {
                int row = wc * 64 + j * 16 + (lane & 15);
                int off = row * 64 + ((kc ^ (row & 7)) << 3);
                bh[j] = *(const short8*)&sBh[off];
                bl[j] = *(const short8*)&sBl[off];
            }
            #pragma unroll
            for (int i2 = 0; i2 < 4; ++i2)
                #pragma unroll
                for (int j = 0; j < 4; ++j) {
                    acc[i2][j] = __builtin_amdgcn_mfma_f32_16x16x32_bf16(ah[i2], bh[j], acc[i2][j], 0, 0, 0);
                    acc[i2][j] = __builtin_amdgcn_mfma_f32_16x16x32_bf16(ah[i2], bl[j], acc[i2][j], 0, 0, 0);
                    acc[i2][j] = __builtin_amdgcn_mfma_f32_16x16x32_bf16(al[i2], bh[j], acc[i2][j], 0, 0, 0);
                }
        }
    }

    // epilogue: C/D layout col=lane&15, row=(lane>>4)*4+reg  [verified m89/m91]
    #pragma unroll
    for (int i2 = 0; i2 < 4; ++i2) {
        #pragma unroll
        for (int j = 0; j < 4; ++j) {
            const int col = colBase + wc * 64 + j * 16 + (lane & 15);
            #pragma unroll
            for (int r = 0; r < 4; ++r) {
                const int row = rowBase + wr * 64 + i2 * 16 + ((lane >> 4) << 2) + r;
                float v = acc[i2][j][r];
                if (MODE == 0) {
                    ushort h, l; split2(v, h, l);
                    O1[(size_t)row * ldc + col] = h;
                    O2[(size_t)row * ldc + col] = l;
                } else {
                    int fc = row >> 6, jj = (row & 63) >> 4, lanelo = row & 15;
                    int cc = col >> 3, ksx = cc >> 2, lanehi = cc & 3, e = col & 7;
                    size_t idx = ((((size_t)fc * 8 + ksx) * 4 + jj) * 64 + lanehi * 16 + lanelo) * 8 + e;
                    O1[idx] = f2bf(v);
                }
            }
        }
    }
}

// pre_gemms: blocks 0..15 -> P split (Ph/Pl); blocks 16..31 -> RT frag layout
__global__ __launch_bounds__(256) void pre_gemms(
    const float* __restrict__ mb, const ushort* __restrict__ wqth, const ushort* __restrict__ wqtl,
    const float* __restrict__ Wo, const ushort* __restrict__ mbh, const ushort* __restrict__ mbl,
    ushort* __restrict__ Ph, ushort* __restrict__ Pl, ushort* __restrict__ RTfrag)
{
    __shared__ ushort smem[32768];   // 64 KiB
    const int b = blockIdx.x;
    if (b < 16) {
        // P[m,e] = sum_f mb[m,f] * WqT[e,f] ; grid (8 cols x 2 rows)
        gemm_body<0>(smem, mb, wqth, wqtl, Ph, Pl, EMB, EMB, b & 7, b >> 3);
    } else {
        // RT[f,m] = sum_e Wo[f,e] * mb[m,e] ; grid (2 cols x 8 rows)
        const int id = b - 16;
        gemm_body<1>(smem, Wo, mbh, mbl, RTfrag, nullptr, EMB, 0, id & 1, id >> 1);
    }
}

// =====================================================================
// Fused: scores (split-precision) + softmax + PV + bias + residual.
// One block per 64 tokens (grid = 512), 256 threads = 4 waves.
// LDS = exactly 80 KiB -> 2 independent blocks/CU (cross-block overlap
// hides the per-K-step barrier drains; m114 mechanism).
// Phase 1: scores[64x256] = x @ (Ph+Pl)^T + c ; wave grid 1x4 (64x64/wave).
// Softmax: 16-lane shfl groups + 4-way cross-wave combine via small LDS.
// Weights -> swizzled sW[64][256].
// Phase 2: out = w @ RT^T + bo + x. ZERO barriers: weight A-frags in regs,
// RT B-frags loaded coalesced from the precomputed fragment-layout buffer
// (L2-resident 512 KB).
// LDS map (ushort idx): ph1 sAh 0..4095, sAl 4096..8191, sBh 8192..24575,
//   sBl 24576..40959; sW overlays 0..16383; redM/redS at 39936../40448..
//   (tail of sBl, used only after phase-1 reads complete).
// =====================================================================
__global__ __launch_bounds__(256, 2) void fused_attn(
    const float* __restrict__ x, const ushort* __restrict__ Ph,
    const ushort* __restrict__ Pl, const float* __restrict__ cvec,
    const ushort* __restrict__ RTfrag, const float* __restrict__ bo,
    float* __restrict__ out)
{
    __shared__ ushort smem[40960];            // 80 KiB exactly
    ushort* sAh = smem;                       // [64][64]
    ushort* sAl = smem + 4096;
    ushort* sBh = smem + 8192;                // [256][64]
    ushort* sBl = smem + 24576;
    ushort* sW  = smem;                       // [64][256] swizzled (phase 2)
    float*  redM = (float*)&smem[39936];      // [4][64] partial max
    float*  redS = (float*)&smem[40448];      // [4][64] partial sum

    const int t = threadIdx.x;
    const int lane = t & 63;
    const int wave = t >> 6;                  // 0..3
    const int wc = wave;                      // phase-1 col group (64 cols each)
    const int rowBase = blockIdx.x * 64;

    const float* Ab = x + (size_t)rowBase * EMB;
    const int cg = ((t & 7) ^ ((t >> 3) & 7)) << 3;

    f32x4 acc[4][4] = {};

    // ---------------- phase 1: scores ----------------
    for (int kt = 0; kt < 16; ++kt) {
        const int k0 = kt << 6;
        __syncthreads();
        // B tiles (Ph/Pl) 256x64: async, swizzled source
        #pragma unroll
        for (int r = 0; r < 8; ++r) {
            int row = r * 32 + (t >> 3);
            async_copy16(Ph + (size_t)row * EMB + k0 + cg, &sBh[(size_t)(r * 256 + wave * 64) * 8]);
            async_copy16(Pl + (size_t)row * EMB + k0 + cg, &sBl[(size_t)(r * 256 + wave * 64) * 8]);
        }
        // A tile 64x64 fp32 -> split -> LDS
        #pragma unroll
        for (int r = 0; r < 2; ++r) {
            int i = r * 256 + t;
            int row = r * 32 + (t >> 3);
            const float* src = Ab + (size_t)row * EMB + k0 + cg;
            float4 f0 = *(const float4*)src;
            float4 f1 = *(const float4*)(src + 4);
            short8 hv, lv; ushort h, l;
            split2(f0.x, h, l); hv[0] = (short)h; lv[0] = (short)l;
            split2(f0.y, h, l); hv[1] = (short)h; lv[1] = (short)l;
            split2(f0.z, h, l); hv[2] = (short)h; lv[2] = (short)l;
            split2(f0.w, h, l); hv[3] = (short)h; lv[3] = (short)l;
            split2(f1.x, h, l); hv[4] = (short)h; lv[4] = (short)l;
            split2(f1.y, h, l); hv[5] = (short)h; lv[5] = (short)l;
            split2(f1.z, h, l); hv[6] = (short)h; lv[6] = (short)l;
            split2(f1.w, h, l); hv[7] = (short)h; lv[7] = (short)l;
            *(short8*)&sAh[(size_t)i * 8] = hv;
            *(short8*)&sAl[(size_t)i * 8] = lv;
        }
        __syncthreads();

        #pragma unroll
        for (int ks = 0; ks < 2; ++ks) {
            const int kc = ks * 4 + (lane >> 4);
            short8 ah[4], al[4], bh[4], bl[4];
            #pragma unroll
            for (int i2 = 0; i2 < 4; ++i2) {
                int row = i2 * 16 + (lane & 15);
                int off = row * 64 + ((kc ^ (row & 7)) << 3);
                ah[i2] = *(const short8*)&sAh[off];
                al[i2] = *(const short8*)&sAl[off];
            }
            #pragma unroll
            for (int j = 0; j < 4; ++j) {
                int row = wc * 64 + j * 16 + (lane & 15);
                int off = row * 64 + ((kc ^ (row & 7)) << 3);
                bh[j] = *(const short8*)&sBh[off];
                bl[j] = *(const short8*)&sBl[off];
            }
            #pragma unroll
            for (int i2 = 0; i2 < 4; ++i2)
                #pragma unroll
                for (int j = 0; j < 4; ++j) {
                    acc[i2][j] = __builtin_amdgcn_mfma_f32_16x16x32_bf16(ah[i2], bh[j], acc[i2][j], 0, 0, 0);
                    acc[i2][j] = __builtin_amdgcn_mfma_f32_16x16x32_bf16(ah[i2], bl[j], acc[i2][j], 0, 0, 0);
                    acc[i2][j] = __builtin_amdgcn_mfma_f32_16x16x32_bf16(al[i2], bh[j], acc[i2][j], 0, 0, 0);
                }
        }
    }

    // ---------------- softmax (64 rows; cols split over 4 waves) ----------------
    // add c[m]
    {
        float cj[4];
        #pragma unroll
        for (int j = 0; j < 4; ++j) cj[j] = cvec[wc * 64 + j * 16 + (lane & 15)];
        #pragma unroll
        for (int i2 = 0; i2 < 4; ++i2)
            #pragma unroll
            for (int j = 0; j < 4; ++j)
                #pragma unroll
                for (int r = 0; r < 4; ++r) acc[i2][j][r] += cj[j];
    }
    // partial row max over this wave's 64 cols (registers only)
    float pmax[4][4];
    #pragma unroll
    for (int i2 = 0; i2 < 4; ++i2)
        #pragma unroll
        for (int r = 0; r < 4; ++r) {
            float m0 = fmaxf(fmaxf(acc[i2][0][r], acc[i2][1][r]),
                             fmaxf(acc[i2][2][r], acc[i2][3][r]));
            #pragma unroll
            for (int off = 8; off; off >>= 1) m0 = fmaxf(m0, __shfl_xor(m0, off, 64));
            pmax[i2][r] = m0;
        }
    __syncthreads();   // bar A: all phase-1 LDS reads complete (redM area safe)
    if ((lane & 15) == 0) {
        #pragma unroll
        for (int i2 = 0; i2 < 4; ++i2)
            #pragma unroll
            for (int r = 0; r < 4; ++r)
                redM[wc * 64 + i2 * 16 + ((lane >> 4) << 2) + r] = pmax[i2][r];
    }
    __syncthreads();   // bar B
    // full max, exp, partial sum
    {
        float psum[4][4];
        #pragma unroll
        for (int i2 = 0; i2 < 4; ++i2)
            #pragma unroll
            for (int r = 0; r < 4; ++r) {
                int R = i2 * 16 + ((lane >> 4) << 2) + r;
                float mx = fmaxf(fmaxf(redM[R], redM[64 + R]),
                                 fmaxf(redM[128 + R], redM[192 + R]));
                float s = 0.f;
                #pragma unroll
                for (int j = 0; j < 4; ++j) {
                    float e = __expf(acc[i2][j][r] - mx);
                    acc[i2][j][r] = e;
                    s += e;
                }
                #pragma unroll
                for (int off = 8; off; off >>= 1) s += __shfl_xor(s, off, 64);
                psum[i2][r] = s;
            }
        if ((lane & 15) == 0) {
            #pragma unroll
            for (int i2 = 0; i2 < 4; ++i2)
                #pragma unroll
                for (int r = 0; r < 4; ++r)
                    redS[wc * 64 + i2 * 16 + ((lane >> 4) << 2) + r] = psum[i2][r];
        }
    }
    __syncthreads();   // bar C
    // normalize -> bf16 weights -> swizzled sW[64][256]
    #pragma unroll
    for (int i2 = 0; i2 < 4; ++i2)
        #pragma unroll
        for (int r = 0; r < 4; ++r) {
            int R = i2 * 16 + ((lane >> 4) << 2) + r;
            float tot = redS[R] + redS[64 + R] + redS[128 + R] + redS[192 + R];
            float inv = 1.0f / tot;
            #pragma unroll
            for (int j = 0; j < 4; ++j) {
                int col = wc * 64 + j * 16 + (lane & 15);
                int cc = col >> 3;
                int slot = (cc & 24) | ((cc & 7) ^ (R & 7));
                sW[R * 256 + slot * 8 + (lane & 7)] = f2bf(acc[i2][j][r] * inv);
            }
        }
    __syncthreads();   // bar D: sW complete

    // ---------------- phase 2: out = w @ RT^T + bo + x (barrier-free) --------
    const int wr2 = wave >> 1;    // 0..1 : token rows wr2*32
    const int wc2 = wave & 1;     // 0..1 : f cols wc2*32 within a 64-f chunk

    // weight A-frags from sW, held in regs across all 16 chunks
    short8 af[2][8];
    #pragma unroll
    for (int i2 = 0; i2 < 2; ++i2) {
        int R = wr2 * 32 + i2 * 16 + (lane & 15);
        #pragma unroll
        for (int ks = 0; ks < 8; ++ks) {
            int cc = ks * 4 + (lane >> 4);
            int slot = (cc & 24) | ((cc & 7) ^ (R & 7));
            af[i2][ks] = *(const short8*)&sW[R * 256 + slot * 8];
        }
    }

    for (int fc = 0; fc < 16; ++fc) {
        f32x4 acc2[2][2] = {};
        #pragma unroll
        for (int ks = 0; ks < 8; ++ks) {
            short8 b[2];
            #pragma unroll
            for (int j = 0; j < 2; ++j) {
                int jj = wc2 * 2 + j;
                b[j] = *(const short8*)&RTfrag[((((size_t)fc * 8 + ks) * 4 + jj) * 64 + lane) * 8];
            }
            #pragma unroll
            for (int i2 = 0; i2 < 2; ++i2)
                #pragma unroll
                for (int j = 0; j < 2; ++j)
                    acc2[i2][j] = __builtin_amdgcn_mfma_f32_16x16x32_bf16(
                        af[i2][ks], b[j], acc2[i2][j], 0, 0, 0);
        }
        // epilogue: + bias + residual, fp32 store (x rows L2/L3-hot from ph1)
        #pragma unroll
        for (int i2 = 0; i2 < 2; ++i2)
            #pragma unroll
            for (int j = 0; j < 2; ++j) {
                int col = fc * 64 + wc2 * 32 + j * 16 + (lane & 15);
                float bcol = bo[col];
                #pragma unroll
                for (int r = 0; r < 4; ++r) {
                    int row = rowBase + wr2 * 32 + i2 * 16 + ((lane >> 4) << 2) + r;
                    out[(size_t)row * EMB + col] =
                        acc2[i2][j][r] + bcol + x[(size_t)row * EMB + col];
                }
            }
    }
}

extern "C" void kernel_launch(void* const* d_in, const int* in_sizes, int n_in,
                              void* d_out, int out_size, void* d_ws, size_t ws_size,
                              hipStream_t stream) {
    const float* x  = (const float*)d_in[0];   // [TOK, EMB]
    const float* mb = (const float*)d_in[1];   // [MSL, EMB]
    const float* Wq = (const float*)d_in[2];   // [EMB, EMB]
    const float* bq = (const float*)d_in[3];   // [EMB]
    const float* Wo = (const float*)d_in[4];   // [EMB, EMB]
    const float* bo = (const float*)d_in[5];   // [EMB]
    float* out = (float*)d_out;                // [TOK, EMB]

    // workspace layout (~6.5 MB), no atomic destinations -> no zeroing
    char* ws = (char*)d_ws;
    size_t o = 0;
    ushort* mbh    = (ushort*)(ws + o); o += (size_t)MSL * EMB * 2;   // mb hi
    ushort* mbl    = (ushort*)(ws + o); o += (size_t)MSL * EMB * 2;   // mb lo
    ushort* wqth   = (ushort*)(ws + o); o += (size_t)EMB * EMB * 2;   // Wq^T hi
    ushort* wqtl   = (ushort*)(ws + o); o += (size_t)EMB * EMB * 2;   // Wq^T lo
    ushort* Ph     = (ushort*)(ws + o); o += (size_t)MSL * EMB * 2;   // P hi [M][E]
    ushort* Pl     = (ushort*)(ws + o); o += (size_t)MSL * EMB * 2;   // P lo
    ushort* RTfrag = (ushort*)(ws + o); o += (size_t)EMB * MSL * 2;   // RT, frag layout
    float*  cvec   = (float*)(ws + o);  o += (size_t)MSL * 4;

    // 1) merged tiny precomputes (transpose+split Wq, split mb, cvec)
    pre_small<<<576, 256, 0, stream>>>(Wq, wqth, wqtl, mb, mbh, mbl, bq, cvec);

    // 2) both folded-projection GEMMs, non-split-K, direct-format epilogues:
    //    P[m,e] hi/lo and RT[f,m] in MFMA-fragment layout
    pre_gemms<<<32, 256, 0, stream>>>(mb, wqth, wqtl, Wo, mbh, mbl, Ph, Pl, RTfrag);

    // 3) fused scores + softmax + PV + bias + residual (64 tokens/block)
    fused_attn<<<TOK / 64, 256, 0, stream>>>(x, Ph, Pl, cvec, RTfrag, bo, out);
}